// Round 1
// baseline (1859.925 us; speedup 1.0000x reference)
//
#include <hip/hip_runtime.h>
#include <hip/hip_bf16.h>
#include <stdint.h>

// ---- problem dims ----
#define SLEN   2048
#define DMODEL 1024
#define DINNER 2048
#define NEXPERT 8
#define NTOK   8192   // B*S = 4*2048

typedef __bf16  b8   __attribute__((ext_vector_type(8)));
typedef float   f4   __attribute__((ext_vector_type(4)));
typedef unsigned short u16x8 __attribute__((ext_vector_type(8)));

// async global->LDS, 16B/lane; LDS dest must be WAVE-UNIFORM base (+lane*16 by HW)
#define GLOAD16(gp, lp) __builtin_amdgcn_global_load_lds( \
    (const __attribute__((address_space(1))) uint32_t*)(gp), \
    (__attribute__((address_space(3))) uint32_t*)(lp), 16, 0, 0)

__device__ __forceinline__ unsigned short f2b(float f) {
  __hip_bfloat16 h = __float2bfloat16(f);
  return __builtin_bit_cast(unsigned short, h);
}
__device__ __forceinline__ float b2f(unsigned short u) {
  uint32_t x = ((uint32_t)u) << 16;
  return __builtin_bit_cast(float, x);
}
__device__ __forceinline__ float silu_f(float v) { return v / (1.0f + __expf(-v)); }

// ---------------- cast fp32 -> bf16 (vectorized float4 -> ushort4) ----------------
__global__ __launch_bounds__(256) void cast_f32_bf16(const float* __restrict__ in,
                                                     unsigned short* __restrict__ out, int n4) {
  int i = blockIdx.x * 256 + threadIdx.x;
  int stride = gridDim.x * 256;
  for (; i < n4; i += stride) {
    float4 v = ((const float4*)in)[i];
    ushort4 o;
    o.x = f2b(v.x); o.y = f2b(v.y); o.z = f2b(v.z); o.w = f2b(v.w);
    ((ushort4*)out)[i] = o;
  }
}

// ---------------- transpose router w1 [128][1024] -> [1024][128] (fp32, tiny) ------
__global__ __launch_bounds__(256) void transpose_w1(const float* __restrict__ in,
                                                    float* __restrict__ out) {
  int idx = blockIdx.x * 256 + threadIdx.x;   // 131072 total
  int k = idx >> 7, hd = idx & 127;
  out[idx] = in[hd * 1024 + k];
}

// ---------------- router: fp32 exact (top-k selection is bf16-fragile) -------------
// 8 tokens / block. rh = silu(h @ w1^T); logits = rh @ w2^T; softmax+top2 -> comb[t][e]
__global__ __launch_bounds__(256) void router_kernel(const float* __restrict__ h,
                                                     const float* __restrict__ w1T,  // [1024][128]
                                                     const float* __restrict__ w2,   // [8][128]
                                                     float* __restrict__ comb) {     // [NTOK][8]
  __shared__ float hs[8 * 1024];     // 32KB: 8 token rows
  __shared__ float red[2 * 8 * 128]; // 8KB : per-half partial rh, then silu(rh)
  __shared__ float lg[8 * 8];
  int tid = threadIdx.x;
  int t0 = blockIdx.x * 8;

  const float4* src = (const float4*)(h + (size_t)t0 * 1024);
  float4* dst = (float4*)hs;
#pragma unroll
  for (int i = 0; i < 8; ++i) dst[tid + i * 256] = src[tid + i * 256];
  __syncthreads();

  int hd = tid & 127, half = tid >> 7;
  float acc[8] = {0.f,0.f,0.f,0.f,0.f,0.f,0.f,0.f};
  int kbeg = half * 512;
  for (int k = kbeg; k < kbeg + 512; ++k) {
    float w = w1T[k * 128 + hd];          // coalesced; w1T streamed once per block
#pragma unroll
    for (int tok = 0; tok < 8; ++tok) acc[tok] += w * hs[tok * 1024 + k];  // LDS broadcast
  }
#pragma unroll
  for (int tok = 0; tok < 8; ++tok) red[(half * 8 + tok) * 128 + hd] = acc[tok];
  __syncthreads();
  if (half == 0) {
#pragma unroll
    for (int tok = 0; tok < 8; ++tok) {
      float v = red[tok * 128 + hd] + red[(8 + tok) * 128 + hd];
      red[tok * 128 + hd] = silu_f(v);
    }
  }
  __syncthreads();
  if (tid < 64) {
    int e = tid & 7, tok = tid >> 3;
    float a = 0.f;
    for (int k = 0; k < 128; ++k) a += red[tok * 128 + k] * w2[e * 128 + k];
    lg[tok * 8 + e] = a;
  }
  __syncthreads();
  if (tid < 8) {
    int tok = tid;
    float* l = lg + tok * 8;
    int i0 = 0; float m0 = l[0];
    for (int e = 1; e < 8; ++e) if (l[e] > m0) { m0 = l[e]; i0 = e; }  // first-max tie-break (= jax)
    int i1 = -1; float m1 = -1e30f;
    for (int e = 0; e < 8; ++e) if (e != i0 && l[e] > m1) { m1 = l[e]; i1 = e; }
    float p1 = __expf(m1 - m0);           // p0 = 1
    float inv = 1.0f / (1.0f + p1);       // renormalized top-2 softmax
    float* c = comb + (size_t)(t0 + tok) * 8;
#pragma unroll
    for (int e = 0; e < 8; ++e) c[e] = 0.f;
    c[i0] = inv; c[i1] = p1 * inv;
  }
}

// ---------------- GEMM1: zx_e = h_bf16 [8192x1024] @ in_w_e^T [4096x1024] -> bf16 --
// m97 structure: 128x128 tile, BK=32, 4 waves (2x2), 16x16x32 MFMA, global_load_lds w16.
__global__ __launch_bounds__(256) void gemm1_kernel(const unsigned short* __restrict__ A,  // [8192][1024]
                                                    const unsigned short* __restrict__ BT, // [4096][1024]
                                                    unsigned short* __restrict__ C) {      // [8192][4096]
  constexpr int BK = 32, K = 1024, LDA = 1024, LDB = 1024, LDC = 4096, NT = 32;
  __shared__ unsigned short As[128 * BK];  // 8KB
  __shared__ unsigned short Bs[128 * BK];  // 8KB

  int nwg = gridDim.x;                       // 2048
  int orig = blockIdx.x;
  int chunk = nwg >> 3;                      // XCD-chunked swizzle: each XCD owns contiguous m-panels
  int logical = (orig & 7) * chunk + (orig >> 3);
  int m0 = (logical / NT) * 128, n0 = (logical % NT) * 128;

  int tid = threadIdx.x, lane = tid & 63, wid = tid >> 6;
  int wm = wid >> 1, wn = wid & 1;

  // staging geometry (fixed per thread): 64B rows (BK=32 bf16)
  int sofs = wid * 2048 + lane * 16;         // byte offset of this lane's 16B in first 1KB issue
  int row0 = sofs >> 6, colel0 = (sofs & 63) >> 1;
  int sofs1 = sofs + 1024;
  int row1 = sofs1 >> 6, colel1 = (sofs1 & 63) >> 1;

  f4 zero4 = {0.f, 0.f, 0.f, 0.f};
  f4 acc[4][4];
#pragma unroll
  for (int i = 0; i < 4; ++i)
#pragma unroll
    for (int j = 0; j < 4; ++j) acc[i][j] = zero4;

  for (int k0 = 0; k0 < K; k0 += BK) {
    __syncthreads();  // previous compute done before overwrite
    GLOAD16(A  + (size_t)(m0 + row0) * LDA + k0 + colel0, (char*)As + wid * 2048);
    GLOAD16(A  + (size_t)(m0 + row1) * LDA + k0 + colel1, (char*)As + wid * 2048 + 1024);
    GLOAD16(BT + (size_t)(n0 + row0) * LDB + k0 + colel0, (char*)Bs + wid * 2048);
    GLOAD16(BT + (size_t)(n0 + row1) * LDB + k0 + colel1, (char*)Bs + wid * 2048 + 1024);
    __syncthreads();  // waits vmcnt(0): staged data visible

    b8 af[4], bf[4];
#pragma unroll
    for (int mf = 0; mf < 4; ++mf) {
      int r = wm * 64 + mf * 16 + (lane & 15);
      af[mf] = __builtin_bit_cast(b8, *(const u16x8*)(As + r * BK + ((lane >> 4) << 3)));
    }
#pragma unroll
    for (int nf = 0; nf < 4; ++nf) {
      int r = wn * 64 + nf * 16 + (lane & 15);
      bf[nf] = __builtin_bit_cast(b8, *(const u16x8*)(Bs + r * BK + ((lane >> 4) << 3)));
    }
#pragma unroll
    for (int mf = 0; mf < 4; ++mf)
#pragma unroll
      for (int nf = 0; nf < 4; ++nf)
        acc[mf][nf] = __builtin_amdgcn_mfma_f32_16x16x32_bf16(af[mf], bf[nf], acc[mf][nf], 0, 0, 0);
  }

  // epilogue: C/D layout col=lane&15, row=(lane>>4)*4+r  [m89/m91-verified]
#pragma unroll
  for (int mf = 0; mf < 4; ++mf)
#pragma unroll
    for (int r = 0; r < 4; ++r) {
      int row = m0 + wm * 64 + mf * 16 + ((lane >> 4) << 2) + r;
#pragma unroll
      for (int nf = 0; nf < 4; ++nf) {
        int col = n0 + wn * 64 + nf * 16 + (lane & 15);
        C[(size_t)row * LDC + col] = f2b(acc[mf][nf][r]);
      }
    }
}

// ---------------- conv(k=4,causal,depthwise) + bias + silu*silu(z) * comb ----------
// one block per token t, expert e; 256 threads x 8 channels
__global__ __launch_bounds__(256) void conv_kernel(const unsigned short* __restrict__ zx,   // [8192][4096]
                                                   const float* __restrict__ conv_w,        // [8][2048][4]
                                                   const float* __restrict__ conv_b,        // [8][2048]
                                                   const float* __restrict__ comb,          // [8192][8]
                                                   unsigned short* __restrict__ xact,       // [8192][8*2048]
                                                   int e) {
  int t = blockIdx.x;
  int s = t & (SLEN - 1);
  int c0 = threadIdx.x * 8;
  float cv = comb[(size_t)t * 8 + e];

  u16x8 z = *(const u16x8*)(zx + (size_t)t * 4096 + c0);
  u16x8 x[4];
  u16x8 zv = {0,0,0,0,0,0,0,0};
#pragma unroll
  for (int j = 0; j < 4; ++j) {
    int srow = s - 3 + j;
    x[j] = (srow >= 0) ? *(const u16x8*)(zx + (size_t)(t - 3 + j) * 4096 + 2048 + c0) : zv;
  }
  const float4* cw = (const float4*)(conv_w + ((size_t)e * 2048 + c0) * 4);
  const float4* cb4 = (const float4*)(conv_b + (size_t)e * 2048 + c0);
  float4 blo = cb4[0], bhi = cb4[1];
  float bias[8] = {blo.x, blo.y, blo.z, blo.w, bhi.x, bhi.y, bhi.z, bhi.w};

  u16x8 res;
#pragma unroll
  for (int i = 0; i < 8; ++i) {
    float4 w = cw[i];
    float xc = bias[i] + w.x * b2f(x[0][i]) + w.y * b2f(x[1][i])
                       + w.z * b2f(x[2][i]) + w.w * b2f(x[3][i]);
    float o = silu_f(xc) * silu_f(b2f(z[i])) * cv;   // comb folded in (linear in out_proj)
    res[i] = f2b(o);
  }
  *(u16x8*)(xact + (size_t)t * (NEXPERT * DINNER) + (size_t)e * DINNER + c0) = res;
}

// ---------------- GEMM2: out = sum_e xact_e @ out_w_e^T  (fp32 out, K=8*2048) ------
__global__ __launch_bounds__(256) void gemm2_kernel(const unsigned short* __restrict__ A,   // [8192][16384]
                                                    const unsigned short* __restrict__ BTa, // [8][1024][2048]
                                                    float* __restrict__ C) {                // [8192][1024]
  constexpr int BK = 32, LDA = 16384, LDB = 2048, LDC = 1024, NT = 8;
  __shared__ unsigned short As[128 * BK];
  __shared__ unsigned short Bs[128 * BK];

  int nwg = gridDim.x;                       // 512
  int orig = blockIdx.x;
  int chunk = nwg >> 3;
  int logical = (orig & 7) * chunk + (orig >> 3);
  int m0 = (logical / NT) * 128, n0 = (logical % NT) * 128;

  int tid = threadIdx.x, lane = tid & 63, wid = tid >> 6;
  int wm = wid >> 1, wn = wid & 1;

  int sofs = wid * 2048 + lane * 16;
  int row0 = sofs >> 6, colel0 = (sofs & 63) >> 1;
  int sofs1 = sofs + 1024;
  int row1 = sofs1 >> 6, colel1 = (sofs1 & 63) >> 1;

  f4 zero4 = {0.f, 0.f, 0.f, 0.f};
  f4 acc[4][4];
#pragma unroll
  for (int i = 0; i < 4; ++i)
#pragma unroll
    for (int j = 0; j < 4; ++j) acc[i][j] = zero4;

  for (int e = 0; e < NEXPERT; ++e) {
    const unsigned short* BT = BTa + (size_t)e * 1024 * 2048;
    int kbase = e * 2048;
    for (int k0 = 0; k0 < 2048; k0 += BK) {
      __syncthreads();
      GLOAD16(A  + (size_t)(m0 + row0) * LDA + kbase + k0 + colel0, (char*)As + wid * 2048);
      GLOAD16(A  + (size_t)(m0 + row1) * LDA + kbase + k0 + colel1, (char*)As + wid * 2048 + 1024);
      GLOAD16(BT + (size_t)(n0 + row0) * LDB + k0 + colel0,         (char*)Bs + wid * 2048);
      GLOAD16(BT + (size_t)(n0 + row1) * LDB + k0 + colel1,         (char*)Bs + wid * 2048 + 1024);
      __syncthreads();

      b8 af[4], bf[4];
#pragma unroll
      for (int mf = 0; mf < 4; ++mf) {
        int r = wm * 64 + mf * 16 + (lane & 15);
        af[mf] = __builtin_bit_cast(b8, *(const u16x8*)(As + r * BK + ((lane >> 4) << 3)));
      }
#pragma unroll
      for (int nf = 0; nf < 4; ++nf) {
        int r = wn * 64 + nf * 16 + (lane & 15);
        bf[nf] = __builtin_bit_cast(b8, *(const u16x8*)(Bs + r * BK + ((lane >> 4) << 3)));
      }
#pragma unroll
      for (int mf = 0; mf < 4; ++mf)
#pragma unroll
        for (int nf = 0; nf < 4; ++nf)
          acc[mf][nf] = __builtin_amdgcn_mfma_f32_16x16x32_bf16(af[mf], bf[nf], acc[mf][nf], 0, 0, 0);
    }
  }

#pragma unroll
  for (int mf = 0; mf < 4; ++mf)
#pragma unroll
    for (int r = 0; r < 4; ++r) {
      int row = m0 + wm * 64 + mf * 16 + ((lane >> 4) << 2) + r;
#pragma unroll
      for (int nf = 0; nf < 4; ++nf) {
        int col = n0 + wn * 64 + nf * 16 + (lane & 15);
        C[(size_t)row * LDC + col] = acc[mf][nf][r];
      }
    }
}

// ---------------- host-side orchestration ----------------
extern "C" void kernel_launch(void* const* d_in, const int* in_sizes, int n_in,
                              void* d_out, int out_size, void* d_ws, size_t ws_size,
                              hipStream_t stream) {
  const float* h      = (const float*)d_in[0];   // [4,2048,1024]
  const float* in_w   = (const float*)d_in[1];   // [8,4096,1024]
  const float* conv_w = (const float*)d_in[2];   // [8,2048,1,4]
  const float* conv_b = (const float*)d_in[3];   // [8,2048]
  const float* out_w  = (const float*)d_in[4];   // [8,1024,2048]
  const float* r_w1   = (const float*)d_in[5];   // [128,1024]
  const float* r_w2   = (const float*)d_in[6];   // [8,128]
  float* out = (float*)d_out;

  char* ws = (char*)d_ws;
  // ws layout (bytes):
  unsigned short* h_bf    = (unsigned short*)(ws);                 // 16,777,216
  unsigned short* inw_bf  = (unsigned short*)(ws + 16777216);      // 67,108,864
  unsigned short* outw_bf = (unsigned short*)(ws + 83886080);      // 33,554,432
  float*          w1T     = (float*)(ws + 117440512);              //    524,288
  float*          comb    = (float*)(ws + 117964800);              //    262,144
  unsigned short* zx_e    = (unsigned short*)(ws + 118226944);     // 67,108,864 (reused per expert)
  unsigned short* xact    = (unsigned short*)(ws + 185335808);     // 268,435,456
  // total 453,771,264 bytes
  if (ws_size < 453771264ull) return;  // insufficient scratch; bail (will fail validation loudly)

  cast_f32_bf16<<<2048, 256, 0, stream>>>(h,     h_bf,    8388608 / 4);
  cast_f32_bf16<<<2048, 256, 0, stream>>>(in_w,  inw_bf,  33554432 / 4);
  cast_f32_bf16<<<2048, 256, 0, stream>>>(out_w, outw_bf, 16777216 / 4);
  transpose_w1<<<512, 256, 0, stream>>>(r_w1, w1T);
  router_kernel<<<1024, 256, 0, stream>>>(h, w1T, r_w2, comb);

  for (int e = 0; e < NEXPERT; ++e) {
    gemm1_kernel<<<2048, 256, 0, stream>>>(h_bf, inw_bf + (size_t)e * 4096 * 1024, zx_e);
    conv_kernel<<<8192, 256, 0, stream>>>(zx_e, conv_w, conv_b, comb, xact, e);
  }
  gemm2_kernel<<<512, 256, 0, stream>>>(xact, outw_bf, out);
}

// Round 3
// 1561.878 us; speedup vs baseline: 1.1908x; 1.1908x over previous
//
#include <hip/hip_runtime.h>
#include <hip/hip_bf16.h>
#include <stdint.h>

// ---- problem dims ----
#define SLEN   2048
#define DMODEL 1024
#define DINNER 2048
#define NEXPERT 8
#define NTOK   8192   // B*S = 4*2048

typedef __bf16  b8   __attribute__((ext_vector_type(8)));
typedef float   f4   __attribute__((ext_vector_type(4)));
typedef unsigned short u16x8 __attribute__((ext_vector_type(8)));

// async global->LDS, 16B/lane; LDS dest must be WAVE-UNIFORM base (+lane*16 by HW)
#define GLOAD16(gp, lp) __builtin_amdgcn_global_load_lds( \
    (const __attribute__((address_space(1))) uint32_t*)(gp), \
    (__attribute__((address_space(3))) uint32_t*)(lp), 16, 0, 0)

#define VM4()   asm volatile("s_waitcnt vmcnt(4)" ::: "memory")
#define VM3()   asm volatile("s_waitcnt vmcnt(3)" ::: "memory")
#define VM0()   asm volatile("s_waitcnt vmcnt(0)" ::: "memory")
#define LGKM0() asm volatile("s_waitcnt lgkmcnt(0)" ::: "memory")
#define FENCE() asm volatile("" ::: "memory")
#define SB()    __builtin_amdgcn_s_barrier()
#define SCHED0() __builtin_amdgcn_sched_barrier(0)

__device__ __forceinline__ unsigned short f2b(float f) {
  __hip_bfloat16 h = __float2bfloat16(f);
  return __builtin_bit_cast(unsigned short, h);
}
__device__ __forceinline__ float b2f(unsigned short u) {
  uint32_t x = ((uint32_t)u) << 16;
  return __builtin_bit_cast(float, x);
}
__device__ __forceinline__ float silu_f(float v) { return v / (1.0f + __expf(-v)); }

// ---------------- cast fp32 -> bf16 ----------------
__global__ __launch_bounds__(256) void cast_f32_bf16(const float* __restrict__ in,
                                                     unsigned short* __restrict__ out, int n4) {
  int i = blockIdx.x * 256 + threadIdx.x;
  int stride = gridDim.x * 256;
  for (; i < n4; i += stride) {
    float4 v = ((const float4*)in)[i];
    ushort4 o;
    o.x = f2b(v.x); o.y = f2b(v.y); o.z = f2b(v.z); o.w = f2b(v.w);
    ((ushort4*)out)[i] = o;
  }
}

// ---------------- transpose router w1 [128][1024] -> [1024][128] ----------------
__global__ __launch_bounds__(256) void transpose_w1(const float* __restrict__ in,
                                                    float* __restrict__ out) {
  int idx = blockIdx.x * 256 + threadIdx.x;
  int k = idx >> 7, hd = idx & 127;
  out[idx] = in[hd * 1024 + k];
}

// ---------------- router: fp32 exact (top-k selection is bf16-fragile) ----------
__global__ __launch_bounds__(256) void router_kernel(const float* __restrict__ h,
                                                     const float* __restrict__ w1T,
                                                     const float* __restrict__ w2,
                                                     float* __restrict__ comb) {
  __shared__ float hs[8 * 1024];
  __shared__ float red[2 * 8 * 128];
  __shared__ float lg[8 * 8];
  int tid = threadIdx.x;
  int t0 = blockIdx.x * 8;

  const float4* src = (const float4*)(h + (size_t)t0 * 1024);
  float4* dst = (float4*)hs;
#pragma unroll
  for (int i = 0; i < 8; ++i) dst[tid + i * 256] = src[tid + i * 256];
  __syncthreads();

  int hd = tid & 127, half = tid >> 7;
  float acc[8] = {0.f,0.f,0.f,0.f,0.f,0.f,0.f,0.f};
  int kbeg = half * 512;
  for (int k = kbeg; k < kbeg + 512; ++k) {
    float w = w1T[k * 128 + hd];
#pragma unroll
    for (int tok = 0; tok < 8; ++tok) acc[tok] += w * hs[tok * 1024 + k];
  }
#pragma unroll
  for (int tok = 0; tok < 8; ++tok) red[(half * 8 + tok) * 128 + hd] = acc[tok];
  __syncthreads();
  if (half == 0) {
#pragma unroll
    for (int tok = 0; tok < 8; ++tok) {
      float v = red[tok * 128 + hd] + red[(8 + tok) * 128 + hd];
      red[tok * 128 + hd] = silu_f(v);
    }
  }
  __syncthreads();
  if (tid < 64) {
    int e = tid & 7, tok = tid >> 3;
    float a = 0.f;
    for (int k = 0; k < 128; ++k) a += red[tok * 128 + k] * w2[e * 128 + k];
    lg[tok * 8 + e] = a;
  }
  __syncthreads();
  if (tid < 8) {
    int tok = tid;
    float* l = lg + tok * 8;
    int i0 = 0; float m0 = l[0];
    for (int e = 1; e < 8; ++e) if (l[e] > m0) { m0 = l[e]; i0 = e; }
    int i1 = -1; float m1 = -1e30f;
    for (int e = 0; e < 8; ++e) if (e != i0 && l[e] > m1) { m1 = l[e]; i1 = e; }
    float p1 = __expf(m1 - m0);
    float inv = 1.0f / (1.0f + p1);
    float* c = comb + (size_t)(t0 + tok) * 8;
#pragma unroll
    for (int e = 0; e < 8; ++e) c[e] = 0.f;
    c[i0] = inv; c[i1] = p1 * inv;
  }
}

// ================= 256-wide 4-phase/K-tile pipelined GEMM (T2+T3+T4+T5) ==========
// C[M x N] = A[M x K] * B^T where B rows are N. 512 thr = 8 waves (2M x 4N).
// BM=256 fixed; BN in {256,128}. BK=64. LDS: A 2x32KB dbuf + B 2x(BN/2*128)x2.
// A-half h: interleaved rows {[0,63]u[128,191]}+64h; B-half h: col groups (BN/8)-interleaved.
// Phase quadrants: P1(A0,B0) P2(A0,B1) P3(A1,B1) P4(A1,B0).
// Stage schedule: P1->A1(t+1) P2->B0(t+1) [other buf]; P3->A0(t+2) P4->B1(t+2) [cur buf].
// Single counted vmcnt per K-tile at P1 (4 loads for BN=256, 3 for BN=128); vmcnt(0) only last.
// Swizzle (both sides): LDS[r][chunk c] = G[r][c ^ (r&7)]; read offset ^ ((lane&7)<<4).
// Verified: read row&7 == lane&7 -> recovers G[r][g]; bank occupancy uniform (8/bank = b128 floor).
template<int BN, int K, int LDA, int LDB, int LDC, int NTN, bool OUTBF, bool BSPLIT>
__global__ __launch_bounds__(512, 2) void gemm256(const unsigned short* __restrict__ A,
                                                  const unsigned short* __restrict__ Bm,
                                                  void* __restrict__ Cv) {
  constexpr int NT = K / 64;
  constexpr int NH = BN / 128;          // N-frags per quadrant (2 | 1)
  constexpr int BH = (BN / 2) * 128;    // B half-slot bytes (16384 | 8192)
  constexpr int BW = BH / 8;            // per-wave stage bytes per B-half
  __shared__ char smem[65536 + 4 * BH];
  char* Asm = smem;
  char* Bsm = smem + 65536;

  const int nwg = gridDim.x;
  const int chunk = nwg >> 3;           // XCD-chunked bijective swizzle (nwg % 8 == 0)
  const int wg = ((int)blockIdx.x & 7) * chunk + ((int)blockIdx.x >> 3);
  const int mt = wg / NTN, nt = wg % NTN;
  const int m0 = mt * 256, n0 = nt * BN;

  const int tid = threadIdx.x, lane = tid & 63, wid = tid >> 6;
  const int wm = wid >> 2, wn = wid & 3;
  const int l15 = lane & 15, hi16 = (lane >> 4) << 4, swx = (lane & 7) << 4;

  // staging geometry (per-thread constants)
  const int l3 = lane >> 3;
  const int scol = ((lane & 7) ^ l3) << 3;            // pre-swizzled source col (elements)
  const int lrA0 = wid * 16 + l3, lrA1 = lrA0 + 8;
  const int rA0 = ((lrA0 >> 6) << 7) + (lrA0 & 63);
  const int rA1 = ((lrA1 >> 6) << 7) + (lrA1 & 63);
  int rB0_ = 0, rB1_ = 0;
  if (BN == 256) {
    int lr0 = wid * 16 + l3, lr1 = lr0 + 8;
    rB0_ = ((lr0 >> 5) << 6) + (lr0 & 31);
    rB1_ = ((lr1 >> 5) << 6) + (lr1 & 31);
  } else {
    int lr0 = wid * 8 + l3;
    rB0_ = ((lr0 >> 4) << 5) + (lr0 & 15);
  }
  const int rB0 = rB0_, rB1 = rB1_;

#define STAGE_A(p, h, k0) do {                                            \
    char* _d = Asm + (p) * 32768 + (h) * 16384 + wid * 2048;              \
    GLOAD16(A + (size_t)(m0 + rA0 + (h) * 64) * LDA + (k0) + scol, _d);   \
    GLOAD16(A + (size_t)(m0 + rA1 + (h) * 64) * LDA + (k0) + scol, _d + 1024); \
  } while (0)

#define STAGE_B(p, h, k0) do {                                            \
    const unsigned short* _B = Bm; int _kk = (k0);                        \
    if (BSPLIT) { _B = Bm + (size_t)((k0) >> 11) * 2097152; _kk = (k0) & 2047; } \
    char* _d = Bsm + (p) * (2 * BH) + (h) * BH + wid * BW;                \
    if (BN == 256) {                                                      \
      GLOAD16(_B + (size_t)(n0 + rB0 + (h) * (BN/8)) * LDB + _kk + scol, _d);        \
      GLOAD16(_B + (size_t)(n0 + rB1 + (h) * (BN/8)) * LDB + _kk + scol, _d + 1024); \
    } else {                                                              \
      GLOAD16(_B + (size_t)(n0 + rB0 + (h) * (BN/8)) * LDB + _kk + scol, _d);        \
    }                                                                     \
  } while (0)

  b8 af[4][2];
  b8 bfr[NH][2];
  f4 acc[8][2 * NH];
#pragma unroll
  for (int i = 0; i < 8; ++i)
#pragma unroll
    for (int j = 0; j < 2 * NH; ++j) { f4 z = {0.f,0.f,0.f,0.f}; acc[i][j] = z; }

#define READ_A(mh, cur) do {                                              \
    const char* _b = Asm + (cur) * 32768 + (mh) * 16384 + (wm * 64 + l15) * 128; \
    _Pragma("unroll") for (int mfl = 0; mfl < 4; ++mfl)                   \
    _Pragma("unroll") for (int ks = 0; ks < 2; ++ks)                      \
      af[mfl][ks] = *(const b8*)(_b + mfl * 2048 + ((ks * 64 + hi16) ^ swx)); \
  } while (0)

#define READ_B(nh, cur) do {                                              \
    const char* _b = Bsm + (cur) * (2 * BH) + (nh) * BH + (wn * (BN/8) + l15) * 128; \
    _Pragma("unroll") for (int nfl = 0; nfl < NH; ++nfl)                  \
    _Pragma("unroll") for (int ks = 0; ks < 2; ++ks)                      \
      bfr[nfl][ks] = *(const b8*)(_b + nfl * 2048 + ((ks * 64 + hi16) ^ swx)); \
  } while (0)

#define MFMA_Q(mh, nh) do {                                               \
    _Pragma("unroll") for (int mfl = 0; mfl < 4; ++mfl)                   \
    _Pragma("unroll") for (int nfl = 0; nfl < NH; ++nfl)                  \
    _Pragma("unroll") for (int ks = 0; ks < 2; ++ks)                      \
      acc[(mh)*4+mfl][(nh)*NH+nfl] = __builtin_amdgcn_mfma_f32_16x16x32_bf16( \
          af[mfl][ks], bfr[nfl][ks], acc[(mh)*4+mfl][(nh)*NH+nfl], 0, 0, 0);  \
  } while (0)

  // prologue (FIFO order matters): A0(0),B1(0),A1(0),B0(0),A0(1),B1(1)
  STAGE_A(0, 0, 0);  STAGE_B(0, 1, 0);  STAGE_A(0, 1, 0);  STAGE_B(0, 0, 0);
  STAGE_A(1, 0, 64); STAGE_B(1, 1, 64);

  for (int t = 0; t < NT; ++t) {
    const int cur = t & 1, nxt = cur ^ 1;
    const int k1 = (t + 1) * 64, k2 = (t + 2) * 64;
    const bool s1 = (t + 1) < NT, s2 = (t + 2) < NT;
    // ---- P1: Q(A0,B0) ----
    if (t == NT - 1) { VM0(); } else if (BN == 256) { VM4(); } else { VM3(); }
    SB(); FENCE();
    READ_A(0, cur); READ_B(0, cur);
    if (s1) STAGE_A(nxt, 1, k1);
    LGKM0(); SCHED0();
    __builtin_amdgcn_s_setprio(1); MFMA_Q(0, 0); __builtin_amdgcn_s_setprio(0);
    // ---- P2: Q(A0,B1) ----
    SB(); FENCE();
    READ_B(1, cur);
    if (s1) STAGE_B(nxt, 0, k1);
    LGKM0(); SCHED0();
    __builtin_amdgcn_s_setprio(1); MFMA_Q(0, 1); __builtin_amdgcn_s_setprio(0);
    // ---- P3: Q(A1,B1) ----
    SB(); FENCE();
    READ_A(1, cur);
    if (s2) STAGE_A(cur, 0, k2);
    LGKM0(); SCHED0();
    __builtin_amdgcn_s_setprio(1); MFMA_Q(1, 1); __builtin_amdgcn_s_setprio(0);
    // ---- P4: Q(A1,B0) ----
    SB(); FENCE();
    READ_B(0, cur);
    if (s2) STAGE_B(cur, 1, k2);
    LGKM0(); SCHED0();
    __builtin_amdgcn_s_setprio(1); MFMA_Q(1, 0); __builtin_amdgcn_s_setprio(0);
  }

  // epilogue: C/D layout col=lane&15, row=(lane>>4)*4+r
  const int r0 = m0 + wm * 128 + ((lane >> 4) << 2);
  const int c0 = n0 + wn * (BN / 4) + l15;
#pragma unroll
  for (int mf = 0; mf < 8; ++mf)
#pragma unroll
    for (int nf = 0; nf < 2 * NH; ++nf)
#pragma unroll
      for (int r = 0; r < 4; ++r) {
        size_t off = (size_t)(r0 + mf * 16 + r) * LDC + (c0 + nf * 16);
        if (OUTBF) ((unsigned short*)Cv)[off] = f2b(acc[mf][nf][r]);
        else       ((float*)Cv)[off] = acc[mf][nf][r];
      }
#undef STAGE_A
#undef STAGE_B
#undef READ_A
#undef READ_B
#undef MFMA_Q
}

// ---------------- conv(k=4,causal,depthwise) + bias + silu*silu(z) * comb --------
__global__ __launch_bounds__(256) void conv_kernel(const unsigned short* __restrict__ zx,
                                                   const float* __restrict__ conv_w,
                                                   const float* __restrict__ conv_b,
                                                   const float* __restrict__ comb,
                                                   unsigned short* __restrict__ xact,
                                                   int e) {
  int t = blockIdx.x;
  int s = t & (SLEN - 1);
  int c0 = threadIdx.x * 8;
  float cv = comb[(size_t)t * 8 + e];

  u16x8 z = *(const u16x8*)(zx + (size_t)t * 4096 + c0);
  u16x8 x[4];
  u16x8 zv = {0,0,0,0,0,0,0,0};
#pragma unroll
  for (int j = 0; j < 4; ++j) {
    int srow = s - 3 + j;
    x[j] = (srow >= 0) ? *(const u16x8*)(zx + (size_t)(t - 3 + j) * 4096 + 2048 + c0) : zv;
  }
  const float4* cw = (const float4*)(conv_w + ((size_t)e * 2048 + c0) * 4);
  const float4* cb4 = (const float4*)(conv_b + (size_t)e * 2048 + c0);
  float4 blo = cb4[0], bhi = cb4[1];
  float bias[8] = {blo.x, blo.y, blo.z, blo.w, bhi.x, bhi.y, bhi.z, bhi.w};

  u16x8 res;
#pragma unroll
  for (int i = 0; i < 8; ++i) {
    float4 w = cw[i];
    float xc = bias[i] + w.x * b2f(x[0][i]) + w.y * b2f(x[1][i])
                       + w.z * b2f(x[2][i]) + w.w * b2f(x[3][i]);
    float o = silu_f(xc) * silu_f(b2f(z[i])) * cv;
    res[i] = f2b(o);
  }
  *(u16x8*)(xact + (size_t)t * (NEXPERT * DINNER) + (size_t)e * DINNER + c0) = res;
}

// ---------------- host-side orchestration ----------------
extern "C" void kernel_launch(void* const* d_in, const int* in_sizes, int n_in,
                              void* d_out, int out_size, void* d_ws, size_t ws_size,
                              hipStream_t stream) {
  const float* h      = (const float*)d_in[0];
  const float* in_w   = (const float*)d_in[1];
  const float* conv_w = (const float*)d_in[2];
  const float* conv_b = (const float*)d_in[3];
  const float* out_w  = (const float*)d_in[4];
  const float* r_w1   = (const float*)d_in[5];
  const float* r_w2   = (const float*)d_in[6];
  float* out = (float*)d_out;

  char* ws = (char*)d_ws;
  unsigned short* h_bf    = (unsigned short*)(ws);                 // 16 MB
  unsigned short* inw_bf  = (unsigned short*)(ws + 16777216);      // 64 MB
  unsigned short* outw_bf = (unsigned short*)(ws + 83886080);      // 32 MB
  float*          w1T     = (float*)(ws + 117440512);              // 512 KB
  float*          comb    = (float*)(ws + 117964800);              // 256 KB
  unsigned short* zx_e    = (unsigned short*)(ws + 118226944);     // 64 MB (reused per expert)
  unsigned short* xact    = (unsigned short*)(ws + 185335808);     // 256 MB
  if (ws_size < 453771264ull) return;

  cast_f32_bf16<<<2048, 256, 0, stream>>>(h,     h_bf,    8388608 / 4);
  cast_f32_bf16<<<2048, 256, 0, stream>>>(in_w,  inw_bf,  33554432 / 4);
  cast_f32_bf16<<<2048, 256, 0, stream>>>(out_w, outw_bf, 16777216 / 4);
  transpose_w1<<<512, 256, 0, stream>>>(r_w1, w1T);
  router_kernel<<<1024, 256, 0, stream>>>(h, w1T, r_w2, comb);

  for (int e = 0; e < NEXPERT; ++e) {
    // zx_e = h_bf [8192x1024] @ in_w_e^T [4096x1024] -> bf16 [8192][4096]
    gemm256<256, 1024, 1024, 1024, 4096, 16, true, false>
        <<<512, 512, 0, stream>>>(h_bf, inw_bf + (size_t)e * 4096 * 1024, zx_e);
    conv_kernel<<<8192, 256, 0, stream>>>(zx_e, conv_w, conv_b, comb, xact, e);
  }
  // out = xact [8192x16384] @ blockdiag(out_w)^T -> fp32 [8192][1024]
  gemm256<128, 16384, 16384, 2048, 1024, 8, false, true>
      <<<256, 512, 0, stream>>>(xact, outw_bf, out);
}